// Round 4
// baseline (44.554 us; speedup 1.0000x reference)
//
#include <hip/hip_runtime.h>
#include <math.h>

// Effective math (cross-attn K/V rows identical per batch element ->
// softmax uniform -> ctx == v; self-attn and QK paths are dead):
//   x   = im_repr @ ca_wv + ca_bv                  [256,768]
//   h   = gelu(x @ fi_w1 + fi_b1)  (exact erf)     [256,256]
//   y   = x + h @ fi_w2 + fi_b2                    [256,768]
//   out = LN(y) * ln_g + ln_b
//
// Round-3: FULLY row-local single kernel. 128 blocks x 512 threads,
// 2 batch rows per block, no grid syncs, no workspace.

#define DMODEL  768
#define ENCD    128
#define HID     256

__global__ __launch_bounds__(512) void qf_one(
    const float* __restrict__ im,   // [256,128]
    const float* __restrict__ wv,   // [128,768]
    const float* __restrict__ bv,   // [768]
    const float* __restrict__ w1,   // [768,256]
    const float* __restrict__ b1,   // [256]
    const float* __restrict__ w2,   // [256,768]
    const float* __restrict__ b2,   // [768]
    const float* __restrict__ gam,  // [768]
    const float* __restrict__ bet,  // [768]
    float* __restrict__ out)        // [256,768]
{
    __shared__ float im_s[2][ENCD];
    __shared__ float x_s[2][DMODEL];
    __shared__ float ph[2][2][HID];   // [k-half][row][j] partial pre-gelu
    __shared__ float h_s[2][HID];
    __shared__ float red[6][2];

    const int t  = threadIdx.x;
    const int r0 = blockIdx.x * 2;

    // ---- load im rows (2 x 128) ----
    if (t < 256) im_s[t >> 7][t & 127] = im[(r0 + (t >> 7)) * ENCD + (t & 127)];
    __syncthreads();

    const int pr = t / 192;            // row for phases 1/3 (threads < 384)
    const int pc = (t % 192) * 4;      // col group (float4)

    // ---- phase 1: x = im @ wv + bv ----
    if (t < 384) {
        float a0 = 0.f, a1 = 0.f, a2 = 0.f, a3 = 0.f;
        #pragma unroll 8
        for (int e = 0; e < ENCD; ++e) {
            float4 w = *(const float4*)(wv + e * DMODEL + pc);
            float iv = im_s[pr][e];
            a0 += iv * w.x; a1 += iv * w.y; a2 += iv * w.z; a3 += iv * w.w;
        }
        float4 bb = *(const float4*)(bv + pc);
        float4 xv;
        xv.x = a0 + bb.x; xv.y = a1 + bb.y; xv.z = a2 + bb.z; xv.w = a3 + bb.w;
        *(float4*)(&x_s[pr][pc]) = xv;
    }
    __syncthreads();

    // ---- phase 2: h = gelu(x @ w1 + b1), split-K 2-way, all 512 threads ----
    {
        const int half = t >> 8;           // 0/1 -> k range
        const int u    = t & 255;
        const int hr   = u >> 7;           // row
        const int j0   = (u & 127) * 2;    // 2 adjacent output cols (float2 loads)
        const int k0   = half * 384;
        float a0 = 0.f, a1 = 0.f, a2 = 0.f, a3 = 0.f;
        #pragma unroll 8
        for (int k = k0; k < k0 + 384; k += 2) {
            float xv0 = x_s[hr][k];
            float xv1 = x_s[hr][k + 1];
            float2 w0 = *(const float2*)(w1 + k * HID + j0);
            float2 w1v = *(const float2*)(w1 + (k + 1) * HID + j0);
            a0 += xv0 * w0.x; a1 += xv0 * w0.y;
            a2 += xv1 * w1v.x; a3 += xv1 * w1v.y;
        }
        ph[half][hr][j0]     = a0 + a2;
        ph[half][hr][j0 + 1] = a1 + a3;
    }
    __syncthreads();
    {
        const int hr = t >> 8, j = t & 255;
        float v = ph[0][hr][j] + ph[1][hr][j] + b1[j];
        h_s[hr][j] = 0.5f * v * (1.f + erff(v * 0.70710678118654752f));
    }
    __syncthreads();

    // ---- phase 3: y = x + h @ w2 + b2 ----
    float y0 = 0.f, y1 = 0.f, y2 = 0.f, y3 = 0.f;
    if (t < 384) {
        float4 acc = *(const float4*)(b2 + pc);
        #pragma unroll 8
        for (int j = 0; j < HID; ++j) {
            float hv = h_s[pr][j];
            float4 w = *(const float4*)(w2 + j * DMODEL + pc);
            acc.x += hv * w.x; acc.y += hv * w.y;
            acc.z += hv * w.z; acc.w += hv * w.w;
        }
        float4 xv = *(const float4*)(&x_s[pr][pc]);
        y0 = xv.x + acc.x; y1 = xv.y + acc.y;
        y2 = xv.z + acc.z; y3 = xv.w + acc.w;
    }

    // ---- phase 4: LayerNorm (row r handled by waves 3r..3r+2) ----
    float s = 0.f, q = 0.f;
    if (t < 384) {
        s = y0 + y1 + y2 + y3;
        q = y0 * y0 + y1 * y1 + y2 * y2 + y3 * y3;
    }
    #pragma unroll
    for (int off = 32; off > 0; off >>= 1) {
        s += __shfl_down(s, off);
        q += __shfl_down(q, off);
    }
    const int lane = t & 63, wave = t >> 6;
    if (lane == 0 && wave < 6) { red[wave][0] = s; red[wave][1] = q; }
    __syncthreads();

    if (t < 384) {
        const int base = pr * 3;
        float ss = red[base][0] + red[base + 1][0] + red[base + 2][0];
        float qq = red[base][1] + red[base + 1][1] + red[base + 2][1];
        float mu   = ss * (1.f / DMODEL);
        float rstd = rsqrtf(qq * (1.f / DMODEL) - mu * mu + 1e-12f);
        float4 gv = *(const float4*)(gam + pc);
        float4 bb = *(const float4*)(bet + pc);
        float4 o;
        o.x = (y0 - mu) * rstd * gv.x + bb.x;
        o.y = (y1 - mu) * rstd * gv.y + bb.y;
        o.z = (y2 - mu) * rstd * gv.z + bb.z;
        o.w = (y3 - mu) * rstd * gv.w + bb.w;
        *(float4*)(out + (r0 + pr) * DMODEL + pc) = o;
    }
}

extern "C" void kernel_launch(void* const* d_in, const int* in_sizes, int n_in,
                              void* d_out, int out_size, void* d_ws, size_t ws_size,
                              hipStream_t stream) {
    const float* im  = (const float*)d_in[0];   // im_repr [256,128]
    const float* wv  = (const float*)d_in[13];  // ca_wv   [128,768]
    const float* bv  = (const float*)d_in[14];  // ca_bv   [768]
    const float* w1  = (const float*)d_in[16];  // fi_w1   [768,256]
    const float* b1  = (const float*)d_in[17];  // fi_b1   [256]
    const float* w2  = (const float*)d_in[18];  // fi_w2   [256,768]
    const float* b2  = (const float*)d_in[19];  // fi_b2   [768]
    const float* g   = (const float*)d_in[20];  // ln_g    [768]
    const float* bt  = (const float*)d_in[21];  // ln_b    [768]
    float* out = (float*)d_out;

    qf_one<<<dim3(128), 512, 0, stream>>>(im, wv, bv, w1, b1, w2, b2, g, bt, out);
}

// Round 5
// 26.353 us; speedup vs baseline: 1.6907x; 1.6907x over previous
//
#include <hip/hip_runtime.h>
#include <math.h>

// Effective math (cross-attn K/V rows identical per batch element ->
// softmax uniform -> ctx == v; self-attn and QK paths are dead):
//   x   = im_repr @ ca_wv + ca_bv                  [256,768]
//   h   = gelu(x @ fi_w1 + fi_b1)  (exact erf)     [256,256]
//   y   = x + h @ fi_w2 + fi_b2                    [256,768]
//   out = LN(y) * ln_g + ln_b
//
// Round-4: 2 kernels.
//  kA (384 blocks): x col-slice (k=128) -> LDS -> w1 partial (k=256).
//  kB (256 blocks): h = gelu(sum p), y = x + h@w2, LayerNorm, store.

#define DMODEL 768
#define ENCD   128
#define HID    256

// ws layout (floats)
#define WS_X 0                 // x [256][768]
#define WS_P (256 * 768)       // p [3][256][256]

// ---- kA: grid(3 kc, 128 rowpairs), 256 thr ----
__global__ __launch_bounds__(256) void kA(
    const float* __restrict__ im,   // [256,128]
    const float* __restrict__ wv,   // [128,768]
    const float* __restrict__ bv,   // [768]
    const float* __restrict__ w1,   // [768,256]
    float* __restrict__ ws)
{
    __shared__ float im_s[2][ENCD];
    __shared__ float x_s[2][256];
    const int t = threadIdx.x, kc = blockIdx.x, r0 = blockIdx.y * 2;

    im_s[t >> 7][t & 127] = im[(r0 + (t >> 7)) * ENCD + (t & 127)];
    __syncthreads();

    // stage 1: x slice, global col = kc*256 + t
    const int col = kc * 256 + t;
    float a0 = 0.f, a1 = 0.f;
    #pragma unroll 16
    for (int e = 0; e < ENCD; ++e) {
        float w = wv[e * DMODEL + col];
        a0 += im_s[0][e] * w;
        a1 += im_s[1][e] * w;
    }
    float b = bv[col];
    a0 += b; a1 += b;
    float* x = ws + WS_X;
    x[(r0 + 0) * DMODEL + col] = a0;
    x[(r0 + 1) * DMODEL + col] = a1;
    x_s[0][t] = a0;
    x_s[1][t] = a1;
    __syncthreads();

    // stage 2: p[kc] = x_s @ w1[kc*256:+256, :]
    float c0 = 0.f, c1 = 0.f;
    const float* w1c = w1 + kc * 256 * HID;
    #pragma unroll 16
    for (int k = 0; k < 256; ++k) {
        float w = w1c[k * HID + t];
        c0 += x_s[0][k] * w;
        c1 += x_s[1][k] * w;
    }
    float* p = ws + WS_P + kc * (256 * HID);
    p[(r0 + 0) * HID + t] = c0;
    p[(r0 + 1) * HID + t] = c1;
}

// ---- kB: grid(256 rows), 256 thr (192 active in matmul) ----
__global__ __launch_bounds__(256) void kB(
    const float* __restrict__ b1,   // [256]
    const float* __restrict__ w2,   // [256,768]
    const float* __restrict__ b2,   // [768]
    const float* __restrict__ gam,  // [768]
    const float* __restrict__ bet,  // [768]
    const float* __restrict__ ws,
    float* __restrict__ out)        // [256,768]
{
    __shared__ float h_s[HID];
    __shared__ float red[3][2];
    const int t = threadIdx.x, r = blockIdx.x;
    const float* p0 = ws + WS_P;
    const float* p1 = p0 + 256 * HID;
    const float* p2 = p1 + 256 * HID;

    {
        int o = r * HID + t;
        float v = p0[o] + p1[o] + p2[o] + b1[t];
        h_s[t] = 0.5f * v * (1.f + erff(v * 0.70710678118654752f));
    }
    __syncthreads();

    const int c0 = 4 * t;
    float y0 = 0.f, y1 = 0.f, y2 = 0.f, y3 = 0.f;
    float s = 0.f, q = 0.f;
    if (t < 192) {
        float4 acc = *(const float4*)(b2 + c0);
        #pragma unroll 8
        for (int j = 0; j < HID; ++j) {
            float hv = h_s[j];
            float4 w = *(const float4*)(w2 + j * DMODEL + c0);
            acc.x += hv * w.x; acc.y += hv * w.y;
            acc.z += hv * w.z; acc.w += hv * w.w;
        }
        const float* x = ws + WS_X + r * DMODEL;
        float4 xv = *(const float4*)(x + c0);
        y0 = xv.x + acc.x; y1 = xv.y + acc.y;
        y2 = xv.z + acc.z; y3 = xv.w + acc.w;
        s = y0 + y1 + y2 + y3;
        q = y0 * y0 + y1 * y1 + y2 * y2 + y3 * y3;
    }
    #pragma unroll
    for (int off = 32; off > 0; off >>= 1) {
        s += __shfl_down(s, off);
        q += __shfl_down(q, off);
    }
    const int lane = t & 63, wave = t >> 6;
    if (lane == 0 && wave < 3) { red[wave][0] = s; red[wave][1] = q; }
    __syncthreads();

    if (t < 192) {
        float ss = red[0][0] + red[1][0] + red[2][0];
        float qq = red[0][1] + red[1][1] + red[2][1];
        float mu   = ss * (1.f / DMODEL);
        float rstd = rsqrtf(qq * (1.f / DMODEL) - mu * mu + 1e-12f);
        float4 gv = *(const float4*)(gam + c0);
        float4 bb = *(const float4*)(bet + c0);
        float4 o;
        o.x = (y0 - mu) * rstd * gv.x + bb.x;
        o.y = (y1 - mu) * rstd * gv.y + bb.y;
        o.z = (y2 - mu) * rstd * gv.z + bb.z;
        o.w = (y3 - mu) * rstd * gv.w + bb.w;
        *(float4*)(out + r * DMODEL + c0) = o;
    }
}

extern "C" void kernel_launch(void* const* d_in, const int* in_sizes, int n_in,
                              void* d_out, int out_size, void* d_ws, size_t ws_size,
                              hipStream_t stream) {
    const float* im  = (const float*)d_in[0];   // im_repr [256,128]
    const float* wv  = (const float*)d_in[13];  // ca_wv   [128,768]
    const float* bv  = (const float*)d_in[14];  // ca_bv   [768]
    const float* w1  = (const float*)d_in[16];  // fi_w1   [768,256]
    const float* b1  = (const float*)d_in[17];  // fi_b1   [256]
    const float* w2  = (const float*)d_in[18];  // fi_w2   [256,768]
    const float* b2  = (const float*)d_in[19];  // fi_b2   [768]
    const float* g   = (const float*)d_in[20];  // ln_g    [768]
    const float* bt  = (const float*)d_in[21];  // ln_b    [768]
    float* out = (float*)d_out;
    float* ws  = (float*)d_ws;

    kA<<<dim3(3, 128), 256, 0, stream>>>(im, wv, bv, w1, ws);
    kB<<<dim3(256), 256, 0, stream>>>(b1, w2, b2, g, bt, ws, out);
}

// Round 6
// 23.961 us; speedup vs baseline: 1.8595x; 1.0998x over previous
//
#include <hip/hip_runtime.h>
#include <math.h>

// Effective math (cross-attn K/V rows identical per batch element ->
// softmax uniform -> ctx == v; self-attn and QK paths are dead):
//   x   = im_repr @ ca_wv + ca_bv                  [256,768]
//   h   = gelu(x @ fi_w1 + fi_b1)  (exact erf)     [256,256]
//   y   = x + h @ fi_w2 + fi_b2                    [256,768]
//   out = LN(y) * ln_g + ln_b
//
// Round-5: same 2-kernel structure, 4x the waves/CU.
//  kA: grid(6 k-slices, 128 rowpairs) x 256 thr  -> 12 waves/CU
//  kB: grid(256 rows) x 768 thr                  -> 12 waves/CU

#define DMODEL 768
#define ENCD   128
#define HID    256
#define KC     6
#define KW     128   // k-slice width (DMODEL / KC)

// ws layout (floats)
#define WS_X 0                   // x [256][768]
#define WS_P (256 * DMODEL)      // p [6][256][256]

__device__ __forceinline__ float gelu_exact(float v) {
    return 0.5f * v * (1.f + erff(v * 0.70710678118654752f));
}

// ---- kA: x col-slice (k=128 over im@wv) -> LDS -> w1 partial (k=128) ----
__global__ __launch_bounds__(256) void kA(
    const float* __restrict__ im,   // [256,128]
    const float* __restrict__ wv,   // [128,768]
    const float* __restrict__ bv,   // [768]
    const float* __restrict__ w1,   // [768,256]
    float* __restrict__ ws)
{
    __shared__ float im_s[2][ENCD];
    __shared__ float x_s[2][KW];
    const int t  = threadIdx.x;
    const int kc = blockIdx.x;
    const int r0 = blockIdx.y * 2;

    im_s[t >> 7][t & 127] = im[(r0 + (t >> 7)) * ENCD + (t & 127)];
    __syncthreads();

    // stage 1: x[r0+row][kc*128 + c], one output per thread
    const int row = t >> 7, c = t & 127;
    const int col = kc * KW + c;
    {
        float a = 0.f;
        #pragma unroll 16
        for (int e = 0; e < ENCD; ++e)
            a += im_s[row][e] * wv[e * DMODEL + col];
        a += bv[col];
        ws[(r0 + row) * DMODEL + col] = a;
        x_s[row][c] = a;
    }
    __syncthreads();

    // stage 2: p[kc][r0+r][j] partial over this k-slice, j = t
    float c0 = 0.f, c1 = 0.f;
    const float* w1c = w1 + kc * KW * HID;
    #pragma unroll 16
    for (int k = 0; k < KW; ++k) {
        float w = w1c[k * HID + t];
        c0 += x_s[0][k] * w;
        c1 += x_s[1][k] * w;
    }
    float* p = ws + WS_P + kc * (256 * HID);
    p[(r0 + 0) * HID + t] = c0;
    p[(r0 + 1) * HID + t] = c1;
}

// ---- kB: h = gelu(sum p + b1); y = x + h@w2 + b2; LN; store ----
__global__ __launch_bounds__(768) void kB(
    const float* __restrict__ b1,   // [256]
    const float* __restrict__ w2,   // [256,768]
    const float* __restrict__ b2,   // [768]
    const float* __restrict__ gam,  // [768]
    const float* __restrict__ bet,  // [768]
    const float* __restrict__ ws,
    float* __restrict__ out)        // [256,768]
{
    __shared__ float h_s[HID];
    __shared__ float red[12][2];
    const int t = threadIdx.x, r = blockIdx.x;

    if (t < HID) {
        float v = b1[t];
        #pragma unroll
        for (int kc = 0; kc < KC; ++kc)
            v += ws[WS_P + kc * (256 * HID) + r * HID + t];
        h_s[t] = gelu_exact(v);
    }
    __syncthreads();

    // y[t] = x[r][t] + sum_j h[j] * w2[j][t] + b2[t]
    float acc0 = b2[t], acc1 = 0.f;
    #pragma unroll 16
    for (int j = 0; j < HID; j += 2) {
        acc0 += h_s[j]     * w2[j * DMODEL + t];
        acc1 += h_s[j + 1] * w2[(j + 1) * DMODEL + t];
    }
    float y = ws[WS_X + r * DMODEL + t] + acc0 + acc1;

    // LayerNorm across 768 threads (12 waves)
    float s = y, q = y * y;
    #pragma unroll
    for (int off = 32; off > 0; off >>= 1) {
        s += __shfl_down(s, off);
        q += __shfl_down(q, off);
    }
    const int lane = t & 63, wave = t >> 6;
    if (lane == 0) { red[wave][0] = s; red[wave][1] = q; }
    __syncthreads();

    float ss = 0.f, qq = 0.f;
    #pragma unroll
    for (int w = 0; w < 12; ++w) { ss += red[w][0]; qq += red[w][1]; }
    float mu   = ss * (1.f / DMODEL);
    float rstd = rsqrtf(qq * (1.f / DMODEL) - mu * mu + 1e-12f);

    out[r * DMODEL + t] = (y - mu) * rstd * gam[t] + bet[t];
}

extern "C" void kernel_launch(void* const* d_in, const int* in_sizes, int n_in,
                              void* d_out, int out_size, void* d_ws, size_t ws_size,
                              hipStream_t stream) {
    const float* im  = (const float*)d_in[0];   // im_repr [256,128]
    const float* wv  = (const float*)d_in[13];  // ca_wv   [128,768]
    const float* bv  = (const float*)d_in[14];  // ca_bv   [768]
    const float* w1  = (const float*)d_in[16];  // fi_w1   [768,256]
    const float* b1  = (const float*)d_in[17];  // fi_b1   [256]
    const float* w2  = (const float*)d_in[18];  // fi_w2   [256,768]
    const float* b2  = (const float*)d_in[19];  // fi_b2   [768]
    const float* g   = (const float*)d_in[20];  // ln_g    [768]
    const float* bt  = (const float*)d_in[21];  // ln_b    [768]
    float* out = (float*)d_out;
    float* ws  = (float*)d_ws;

    kA<<<dim3(6, 128), 256, 0, stream>>>(im, wv, bv, w1, ws);
    kB<<<dim3(256), 768, 0, stream>>>(b1, w2, b2, g, bt, ws, out);
}